// Round 1
// 2205.396 us; speedup vs baseline: 1.3592x; 1.3592x over previous
//
#include <hip/hip_runtime.h>
#include <hip/hip_bf16.h>

#define SEQ 2048
#define DM  1024
#define NH  16
#define DK  64
#define QT  16    // q rows per attn_scores block
#define KC  256   // keys per staged chunk
#define OUT_ELEMS ((size_t)2 * SEQ * DM)   // 4194304, element offset of attn in d_out

// ---- dtype-dynamic load/store (flag f: 1 = fp32, 0 = bf16) ----
struct SrcF {
    const float* p; size_t base;
    __device__ float ld(size_t i, int) const { return p[base + i]; }
};
struct SrcDyn {
    const void* p; size_t base;
    __device__ float ld(size_t i, int f) const {
        return f ? ((const float*)p)[base + i]
                 : __bfloat162float(((const __hip_bfloat16*)p)[base + i]);
    }
};
struct DstF {
    float* p; size_t base;
    __device__ void st(size_t i, float v, int) const { p[base + i] = v; }
};
struct DstDyn {
    void* p; size_t base;
    __device__ void st(size_t i, float v, int f) const {
        if (f) ((float*)p)[base + i] = v;
        else   ((__hip_bfloat16*)p)[base + i] = __float2bfloat16(v);
    }
};

// ---- dtype detection: sample 64 words of query, vote on bf16 exponent stats ----
__global__ void detect_dtype(const unsigned int* q, int* flag) {
    unsigned w = q[(size_t)threadIdx.x * 30011 + 7];   // max 1,890,700 < 2M words (safe for bf16 buf)
    int e = (w >> 7) & 0xFF;                           // exponent field of low-half bf16
    int inr = (e >= 115 && e <= 131) ? 1 : 0;          // N(0,1) bf16 lands here w.p. >0.999
    unsigned long long bal = __ballot(inr);
    if (threadIdx.x == 0) *flag = (__popcll(bal) >= 32) ? 0 : 1;  // 0=bf16, 1=fp32
}

// C[M,N] = A[M,K] @ W[K,N] (+ bias). 64x64 tile, BK=32, 4x4 micro-tile, 256 thr.
// z-batched: A/C advance by sAz/sCz per blockIdx.z, W by sWz per (z / wzdiv).
template <class SA, class SW, class SB, class DC>
__global__ __launch_bounds__(256) void gemm_bias(
    SA A, SW W, SB Bv, int hasBias, DC C,
    int M, int N, int K, size_t sAz, size_t sWz, int wzdiv, size_t sCz,
    const int* __restrict__ dflag)
{
    const int f = *dflag;
    const size_t aZ = (size_t)blockIdx.z * sAz;
    const size_t wZ = (size_t)(blockIdx.z / wzdiv) * sWz;
    const size_t cZ = (size_t)blockIdx.z * sCz;

    __shared__ float As[32][68];   // [k][m]
    __shared__ float Bs[32][68];   // [k][n]
    const int tid = threadIdx.x;
    const int tx = tid & 15, ty = tid >> 4;
    const int m0 = blockIdx.y * 64, n0 = blockIdx.x * 64;

    float acc[4][4];
#pragma unroll
    for (int i = 0; i < 4; ++i)
#pragma unroll
        for (int j = 0; j < 4; ++j) acc[i][j] = 0.f;

    for (int k0 = 0; k0 < K; k0 += 32) {
        __syncthreads();
#pragma unroll
        for (int r = 0; r < 8; ++r) {
            int i = tid + 256 * r;            // 0..2047
            int mm = i >> 5, kk = i & 31;     // A tile: 64 m x 32 k
            As[kk][mm] = A.ld(aZ + (size_t)(m0 + mm) * K + (k0 + kk), f);
            int kk2 = i >> 6, nn = i & 63;    // W tile: 32 k x 64 n
            Bs[kk2][nn] = W.ld(wZ + (size_t)(k0 + kk2) * N + (n0 + nn), f);
        }
        __syncthreads();
#pragma unroll
        for (int kk = 0; kk < 32; ++kk) {
            float4 a4 = *(const float4*)&As[kk][ty * 4];
            float4 b4 = *(const float4*)&Bs[kk][tx * 4];
            float a[4] = {a4.x, a4.y, a4.z, a4.w};
            float b[4] = {b4.x, b4.y, b4.z, b4.w};
#pragma unroll
            for (int i = 0; i < 4; ++i)
#pragma unroll
                for (int j = 0; j < 4; ++j) acc[i][j] += a[i] * b[j];
        }
    }

#pragma unroll
    for (int i = 0; i < 4; ++i) {
        int mm = m0 + ty * 4 + i;
#pragma unroll
        for (int j = 0; j < 4; ++j) {
            int nn = n0 + tx * 4 + j;
            float vb = hasBias ? Bv.ld((size_t)nn, f) : 0.f;
            C.st(cZ + (size_t)mm * N + nn, acc[i][j] + vb, f);
        }
    }
}

// K transpose: Kt[b][dk][key] <- Kf[b][key][dk], per-64-key tile via LDS
__global__ __launch_bounds__(256) void transpose_k(
    const float* __restrict__ Kf, float* __restrict__ Kt)
{
    __shared__ float tile[64][65];
    const int tid = threadIdx.x;
    const int b = blockIdx.y;
    const size_t kbase = (size_t)b * SEQ * DK + (size_t)blockIdx.x * 64 * DK;
#pragma unroll
    for (int r = 0; r < 4; ++r) {
        int idx = tid + 256 * r;              // 0..1023 float4 units
        int key = idx >> 4, dd = (idx & 15) * 4;
        *(float4*)&tile[key][dd] = *(const float4*)(Kf + kbase + (size_t)key * DK + dd);
    }
    __syncthreads();
    const size_t tbase = (size_t)b * DK * SEQ + (size_t)blockIdx.x * 64;
#pragma unroll
    for (int r = 0; r < 4; ++r) {
        int idx = tid + 256 * r;
        int kk = idx >> 4, k4 = (idx & 15) * 4;
        float4 v;
        v.x = tile[k4 + 0][kk];
        v.y = tile[k4 + 1][kk];
        v.z = tile[k4 + 2][kk];
        v.w = tile[k4 + 3][kk];
        *(float4*)(Kt + tbase + (size_t)kk * SEQ + k4) = v;
    }
}

// scores + softmax + attn write, SINGLE pass, scores held in registers.
// Block = 16 q rows x full 2048 keys for one (b,h). 4 waves; wave w owns rows
// w*4..w*4+3; lane l owns keys c*KC + l*4 .. +3 per chunk. s[4][32] in VGPRs.
__global__ __launch_bounds__(256, 2) void attn_scores(
    const float* __restrict__ Qf, const float* __restrict__ Kt,
    void* __restrict__ outp, const int* __restrict__ dflag)
{
    const int f = *dflag;
    __shared__ float Ks[DK][KC];     // 64 KB, [dk][key] transposed chunk
    __shared__ float QsT[DK][QT];    // 4 KB,  [dk][row] transposed Q tile

    const int tid = threadIdx.x;
    const int l = tid & 63, w = tid >> 6;
    const int q0 = blockIdx.x * QT;
    const int h = blockIdx.y, b = blockIdx.z;

    const float* Qbase = Qf + (size_t)b * SEQ * DM + (size_t)h * DK;
    const float* Ktb   = Kt + (size_t)b * DK * SEQ;

    // ---- stage Q tile (16x64) row-major into Ks-as-temp, transpose into QsT
    {
        float* Qtmp = &Ks[0][0];                 // 16 rows, stride 68
        int qq = tid >> 4, dd = (tid & 15) * 4;
        *(float4*)&Qtmp[qq * 68 + dd] =
            *(const float4*)(Qbase + (size_t)(q0 + qq) * DM + dd);
        __syncthreads();
        int kk = tid >> 2, g = tid & 3;          // write addr = t*16B: conflict-free
        float4 v;
        v.x = Qtmp[(g * 4 + 0) * 68 + kk];
        v.y = Qtmp[(g * 4 + 1) * 68 + kk];
        v.z = Qtmp[(g * 4 + 2) * 68 + kk];
        v.w = Qtmp[(g * 4 + 3) * 68 + kk];
        *(float4*)&QsT[kk][g * 4] = v;
    }

    float s[4][32];                              // [row][key slot c*4+j]
#pragma unroll
    for (int i = 0; i < 4; ++i)
#pragma unroll
        for (int j = 0; j < 32; ++j) s[i][j] = 0.f;

#pragma unroll
    for (int c = 0; c < SEQ / KC; ++c) {
        __syncthreads();                         // prev chunk fully consumed
#pragma unroll
        for (int r = 0; r < 16; ++r) {
            int idx = tid + 256 * r;             // 0..4095 float4 units
            int kk = idx >> 6, k4 = (idx & 63) * 4;
            *(float4*)&Ks[kk][k4] =
                *(const float4*)(Ktb + (size_t)kk * SEQ + c * KC + k4);
        }
        __syncthreads();

        float acc[4][4];
#pragma unroll
        for (int i = 0; i < 4; ++i)
#pragma unroll
            for (int j = 0; j < 4; ++j) acc[i][j] = 0.f;

#pragma unroll 4
        for (int kk = 0; kk < DK; ++kk) {
            float4 q4 = *(const float4*)&QsT[kk][w * 4];   // wave-uniform broadcast
            float4 k4 = *(const float4*)&Ks[kk][l * 4];    // contiguous, conflict-free
            float qa[4] = {q4.x, q4.y, q4.z, q4.w};
            float kb[4] = {k4.x, k4.y, k4.z, k4.w};
#pragma unroll
            for (int i = 0; i < 4; ++i)
#pragma unroll
                for (int j = 0; j < 4; ++j) acc[i][j] += qa[i] * kb[j];
        }
#pragma unroll
        for (int i = 0; i < 4; ++i)
#pragma unroll
            for (int j = 0; j < 4; ++j) s[i][c * 4 + j] = acc[i][j];
    }

    // scale by 1/sqrt(DK) = 0.125
#pragma unroll
    for (int i = 0; i < 4; ++i)
#pragma unroll
        for (int j = 0; j < 32; ++j) s[i][j] *= 0.125f;

    // per-row softmax (row fully owned by this wave) + coalesced write
    const size_t obase = ((size_t)(b * NH + h) * SEQ + (size_t)(q0 + w * 4)) * SEQ;
#pragma unroll
    for (int i = 0; i < 4; ++i) {
        float m = s[i][0];
#pragma unroll
        for (int j = 1; j < 32; ++j) m = fmaxf(m, s[i][j]);
#pragma unroll
        for (int off = 1; off < 64; off <<= 1)
            m = fmaxf(m, __shfl_xor(m, off));

        float lsum = 0.f;
#pragma unroll
        for (int j = 0; j < 32; ++j) {
            float e = expf(s[i][j] - m);
            s[i][j] = e;
            lsum += e;
        }
#pragma unroll
        for (int off = 1; off < 64; off <<= 1)
            lsum += __shfl_xor(lsum, off);
        const float inv = 1.f / lsum;

        const size_t rb = obase + (size_t)i * SEQ;
        if (f) {
            float* op = (float*)outp + OUT_ELEMS + rb;
#pragma unroll
            for (int c = 0; c < SEQ / KC; ++c) {
                float4 v;
                v.x = s[i][c * 4 + 0] * inv;
                v.y = s[i][c * 4 + 1] * inv;
                v.z = s[i][c * 4 + 2] * inv;
                v.w = s[i][c * 4 + 3] * inv;
                *(float4*)(op + c * KC + l * 4) = v;
            }
        } else {
            __hip_bfloat16* op = (__hip_bfloat16*)outp + OUT_ELEMS + rb;
#pragma unroll
            for (int c = 0; c < SEQ / KC; ++c) {
                __hip_bfloat162 p0, p1;
                p0.x = __float2bfloat16(s[i][c * 4 + 0] * inv);
                p0.y = __float2bfloat16(s[i][c * 4 + 1] * inv);
                p1.x = __float2bfloat16(s[i][c * 4 + 2] * inv);
                p1.y = __float2bfloat16(s[i][c * 4 + 3] * inv);
                *(__hip_bfloat162*)(op + c * KC + l * 4)     = p0;
                *(__hip_bfloat162*)(op + c * KC + l * 4 + 2) = p1;
            }
        }
    }
}

extern "C" void kernel_launch(void* const* d_in, const int* in_sizes, int n_in,
                              void* d_out, int out_size, void* d_ws, size_t ws_size,
                              hipStream_t stream) {
    const void* query = d_in[0];
    const void* key   = d_in[1];
    const void* value = d_in[2];
    const void* w_q = d_in[3];
    const void* b_q = d_in[4];
    const void* w_k = d_in[5];
    const void* b_k = d_in[6];
    const void* w_v = d_in[7];
    const void* b_v = d_in[8];
    const void* w_o = d_in[9];
    const void* b_o = d_in[10];

    const size_t M = (size_t)2 * SEQ;   // 4096 rows
    int*   flag = (int*)d_ws;
    float* Qf  = (float*)d_ws + 16;     // [4096,1024]
    float* Kf  = Qf + M * DM;           // [4096,64]
    float* Vf  = Kf + M * DK;           // [4096,64]
    float* AOf = Vf + M * DK;           // heads, FLAT [B,H,S,DK] = [4096,1024]
    // Kt aliases the front of AOf: Kt is consumed by attn_scores, which completes
    // (stream-ordered) before step 3 writes AOf. [B][DK][SEQ] = 1 MB.
    float* Kt  = AOf;

    // 0) detect input/output element type (writes flag: 1=fp32, 0=bf16)
    detect_dtype<<<1, 64, 0, stream>>>((const unsigned int*)query, flag);

    // 1) projections (fp32 results in ws)
    gemm_bias<<<dim3(16, 64, 1), 256, 0, stream>>>(
        SrcDyn{query, 0}, SrcDyn{w_q, 0}, SrcDyn{b_q, 0}, 1, DstF{Qf, 0},
        (int)M, DM, DM, (size_t)0, (size_t)0, 1, (size_t)0, flag);
    gemm_bias<<<dim3(1, 64, 1), 256, 0, stream>>>(
        SrcDyn{key, 0}, SrcDyn{w_k, 0}, SrcDyn{b_k, 0}, 1, DstF{Kf, 0},
        (int)M, DK, DM, (size_t)0, (size_t)0, 1, (size_t)0, flag);
    gemm_bias<<<dim3(1, 64, 1), 256, 0, stream>>>(
        SrcDyn{value, 0}, SrcDyn{w_v, 0}, SrcDyn{b_v, 0}, 1, DstF{Vf, 0},
        (int)M, DK, DM, (size_t)0, (size_t)0, 1, (size_t)0, flag);

    // 1b) K -> Kt transposed [b][dk][key] for coalesced chunk staging
    transpose_k<<<dim3(SEQ / 64, 2), 256, 0, stream>>>(Kf, Kt);

    // 2) softmax(QK^T/8) -> attn region of d_out (element offset OUT_ELEMS)
    attn_scores<<<dim3(SEQ / QT, NH, 2), 256, 0, stream>>>(
        Qf, Kt, d_out, flag);

    // 3) heads[bh] = attn[bh] @ V[b]  -> AOf flat [B,H,S,DK]
    gemm_bias<<<dim3(1, SEQ / 64, 2 * NH), 256, 0, stream>>>(
        SrcDyn{d_out, OUT_ELEMS}, SrcF{Vf, 0}, SrcF{Vf, 0}, 0, DstF{AOf, 0},
        SEQ, DK, SEQ, (size_t)SEQ * SEQ, (size_t)SEQ * DK, NH, (size_t)SEQ * DK, flag);

    // 4) out = reshape(heads) @ w_o + b_o -> out region of d_out
    gemm_bias<<<dim3(16, 64, 1), 256, 0, stream>>>(
        SrcF{AOf, 0}, SrcDyn{w_o, 0}, SrcDyn{b_o, 0}, 1, DstDyn{d_out, 0},
        (int)M, DM, DM, (size_t)0, (size_t)0, 1, (size_t)0, flag);
}

// Round 2
// 1137.277 us; speedup vs baseline: 2.6358x; 1.9392x over previous
//
#include <hip/hip_runtime.h>
#include <hip/hip_bf16.h>

#define SEQ 2048
#define DM  1024
#define NH  16
#define DK  64
#define QT  16    // q rows per attn_scores block
#define KC  256   // keys per staged chunk in attn_scores
#define OUT_ELEMS ((size_t)2 * SEQ * DM)   // 4194304, element offset of attn in d_out

typedef unsigned short u16;
typedef __bf16 bf16x8 __attribute__((ext_vector_type(8)));
typedef float  f32x4  __attribute__((ext_vector_type(4)));
typedef u16    u16x8  __attribute__((ext_vector_type(8)));
typedef u16    u16x4  __attribute__((ext_vector_type(4)));

__device__ __forceinline__ u16 f2bs(float x) {
    union { __hip_bfloat16 h; u16 s; } u; u.h = __float2bfloat16(x); return u.s;
}
__device__ __forceinline__ float bs2f(u16 s) {
    union { __hip_bfloat16 h; u16 s; } u; u.s = s; return __bfloat162float(u.h);
}
// dtype-dynamic scalar load (f: 1 = fp32, 0 = bf16)
__device__ __forceinline__ float ldf(const void* p, size_t i, int f) {
    return f ? ((const float*)p)[i] : bs2f(((const u16*)p)[i]);
}

// ---- dtype detection: sample 64 words of query, vote on bf16 exponent stats ----
__global__ void detect_dtype(const unsigned int* q, int* flag) {
    unsigned w = q[(size_t)threadIdx.x * 30011 + 7];   // max 1,890,700 < 2M words (safe for bf16 buf)
    int e = (w >> 7) & 0xFF;                           // exponent field of low-half bf16
    int inr = (e >= 115 && e <= 131) ? 1 : 0;          // N(0,1) bf16 lands here w.p. >0.999
    unsigned long long bal = __ballot(inr);
    if (threadIdx.x == 0) *flag = (__popcll(bal) >= 32) ? 0 : 1;  // 0=bf16, 1=fp32
}

// ---- elementwise convert (or copy) to bf16, 8 elems/thread ----
__global__ __launch_bounds__(256) void conv_bf16(const void* __restrict__ src,
                                                 u16* __restrict__ dst,
                                                 const int* __restrict__ dflag) {
    const int f = *dflag;
    size_t i = ((size_t)blockIdx.x * 256 + threadIdx.x) * 8;
    if (f) {
        const float* s = (const float*)src + i;
        float4 a = *(const float4*)s, b = *(const float4*)(s + 4);
        u16x8 u;
        u[0] = f2bs(a.x); u[1] = f2bs(a.y); u[2] = f2bs(a.z); u[3] = f2bs(a.w);
        u[4] = f2bs(b.x); u[5] = f2bs(b.y); u[6] = f2bs(b.z); u[7] = f2bs(b.w);
        *(u16x8*)(dst + i) = u;
    } else {
        *(u16x8*)(dst + i) = *(const u16x8*)((const u16*)src + i);
    }
}

// ---- W[K][N] (dyn dtype) -> WT[N][K] bf16, 64x64 LDS tile ----
__global__ __launch_bounds__(256) void conv_wT(const void* __restrict__ W, u16* __restrict__ WT,
                                               int Kd, int Nd, const int* __restrict__ dflag) {
    const int f = *dflag;
    __shared__ float t[64][65];
    const int tid = threadIdx.x;
    const int k0 = blockIdx.y * 64, n0 = blockIdx.x * 64;
#pragma unroll
    for (int it = 0; it < 4; ++it) {
        int idx = tid + 256 * it;
        int rr = idx >> 4, c4 = (idx & 15) * 4;
        size_t gi = (size_t)(k0 + rr) * Nd + n0 + c4;
        if (f) {
            float4 v = *(const float4*)((const float*)W + gi);
            t[rr][c4] = v.x; t[rr][c4 + 1] = v.y; t[rr][c4 + 2] = v.z; t[rr][c4 + 3] = v.w;
        } else {
            u16x4 u = *(const u16x4*)((const u16*)W + gi);
            t[rr][c4] = bs2f(u[0]); t[rr][c4 + 1] = bs2f(u[1]);
            t[rr][c4 + 2] = bs2f(u[2]); t[rr][c4 + 3] = bs2f(u[3]);
        }
    }
    __syncthreads();
#pragma unroll
    for (int it = 0; it < 4; ++it) {
        int idx = tid + 256 * it;
        int rr = idx >> 4, c4 = (idx & 15) * 4;
        u16x4 u;
        u[0] = f2bs(t[c4][rr]);     u[1] = f2bs(t[c4 + 1][rr]);
        u[2] = f2bs(t[c4 + 2][rr]); u[3] = f2bs(t[c4 + 3][rr]);
        *(u16x4*)(WT + (size_t)(n0 + rr) * Kd + k0 + c4) = u;
    }
}

// ---- MFMA GEMM: C[M,N] = A[M,K](bf16) @ BT[N,K](bf16)^T + bias ----
// 128x128 tile, BK=64, 4 waves (2x2 of 64x64), 16x16x32 bf16 MFMA.
// LDS tiles XOR-swizzled (byte ^= (row&7)<<4) for conflict-free ds_read_b128.
// outMode: 0 = fp32 always, 1 = dyn dtype (d_out).
__global__ __launch_bounds__(256) void gemm_mfma(
    const u16* __restrict__ A, const u16* __restrict__ BT,
    const void* __restrict__ bias, void* __restrict__ C, int outMode,
    int Md, int Nd, int Kd, const int* __restrict__ dflag)
{
    const int f = *dflag;
    __shared__ u16 Als[128 * 64];
    __shared__ u16 Bls[128 * 64];
    const int tid = threadIdx.x;
    const int lane = tid & 63, wid = tid >> 6;
    const int wr = wid >> 1, wc = wid & 1;
    const int m0 = blockIdx.y * 128, n0 = blockIdx.x * 128;

    // staging addressing: tile is 128 rows x 128 bytes (64 bf16)
    const char* pa[4]; const char* pb[4]; int lof[4];
#pragma unroll
    for (int it = 0; it < 4; ++it) {
        int tb = wid * 4096 + it * 1024 + lane * 16;   // byte within 16 KB tile
        int r = tb >> 7, o = tb & 127;
        lof[it] = (r << 7) | (o ^ ((r & 7) << 4));     // swizzled LDS dest
        pa[it] = (const char*)(A  + (size_t)(m0 + r) * Kd) + o;  // linear global src
        pb[it] = (const char*)(BT + (size_t)(n0 + r) * Kd) + o;
    }

    f32x4 acc[4][4];
#pragma unroll
    for (int i = 0; i < 4; ++i)
#pragma unroll
        for (int j = 0; j < 4; ++j) acc[i][j] = (f32x4){0.f, 0.f, 0.f, 0.f};

    u16x8 ra[4], rb[4];
#pragma unroll
    for (int it = 0; it < 4; ++it) {
        ra[it] = *(const u16x8*)(pa[it]);
        rb[it] = *(const u16x8*)(pb[it]);
    }
    const int NT = Kd >> 6;
    for (int kt = 0; kt < NT; ++kt) {
        __syncthreads();                       // prev tile fully consumed
#pragma unroll
        for (int it = 0; it < 4; ++it) {
            *(u16x8*)((char*)Als + lof[it]) = ra[it];
            *(u16x8*)((char*)Bls + lof[it]) = rb[it];
        }
        if (kt + 1 < NT) {                     // prefetch next tile (in flight over compute)
#pragma unroll
            for (int it = 0; it < 4; ++it) {
                ra[it] = *(const u16x8*)(pa[it] + (kt + 1) * 128);
                rb[it] = *(const u16x8*)(pb[it] + (kt + 1) * 128);
            }
        }
        __syncthreads();
#pragma unroll
        for (int ks = 0; ks < 2; ++ks) {
            const int kb = ks * 64 + ((lane >> 4) << 4);   // byte-in-row for this lane's k-slice
            bf16x8 afr[4], bfr[4];
#pragma unroll
            for (int mi = 0; mi < 4; ++mi) {
                int rr = wr * 64 + mi * 16 + (lane & 15);
                afr[mi] = *(const bf16x8*)((const char*)Als + ((rr << 7) | (kb ^ ((rr & 7) << 4))));
            }
#pragma unroll
            for (int ni = 0; ni < 4; ++ni) {
                int rr = wc * 64 + ni * 16 + (lane & 15);
                bfr[ni] = *(const bf16x8*)((const char*)Bls + ((rr << 7) | (kb ^ ((rr & 7) << 4))));
            }
#pragma unroll
            for (int mi = 0; mi < 4; ++mi)
#pragma unroll
                for (int ni = 0; ni < 4; ++ni)
                    acc[mi][ni] = __builtin_amdgcn_mfma_f32_16x16x32_bf16(
                        afr[mi], bfr[ni], acc[mi][ni], 0, 0, 0);
        }
    }

    // epilogue: C/D layout col=lane&15, row=(lane>>4)*4+reg [m89-verified]
#pragma unroll
    for (int mi = 0; mi < 4; ++mi)
#pragma unroll
        for (int ni = 0; ni < 4; ++ni) {
            int n = n0 + wc * 64 + ni * 16 + (lane & 15);
            float vb = ldf(bias, (size_t)n, f);
#pragma unroll
            for (int r = 0; r < 4; ++r) {
                int m = m0 + wr * 64 + mi * 16 + ((lane >> 4) << 2) + r;
                float v = acc[mi][ni][r] + vb;
                size_t ci = (size_t)m * Nd + n;
                if (outMode == 0)      ((float*)C)[ci] = v;
                else if (f)            ((float*)C)[ci] = v;
                else ((__hip_bfloat16*)C)[ci] = __float2bfloat16(v);
            }
        }
}

// ---- K/V projection, direct-fragment MFMA (N=64: no A reuse -> no LDS) ----
// z=0: KT[b][dk][s] fp32 (transposed, for attn_scores); z=1: VT[b][dk][s] bf16 (for PV).
__global__ __launch_bounds__(256) void proj_kv(
    const u16* __restrict__ Xk, const u16* __restrict__ Xv,
    const u16* __restrict__ WkT, const u16* __restrict__ WvT,
    const void* __restrict__ bk, const void* __restrict__ bvv,
    float* __restrict__ KT, u16* __restrict__ VTo,
    const int* __restrict__ dflag)
{
    const int f = *dflag;
    const int isV = blockIdx.z;
    const u16* X  = isV ? Xv : Xk;
    const u16* WT = isV ? WvT : WkT;
    const void* bb = isV ? bvv : bk;
    const int lane = threadIdx.x & 63, wid = threadIdx.x >> 6;
    const int m0 = blockIdx.x * 64 + wid * 16;
    const int rA = m0 + (lane & 15);
    const int kel = (lane >> 4) * 8;
    const char* pa = (const char*)(X + (size_t)rA * 1024 + kel);
    const char* pb[4];
#pragma unroll
    for (int ni = 0; ni < 4; ++ni)
        pb[ni] = (const char*)(WT + (size_t)(ni * 16 + (lane & 15)) * 1024 + kel);

    f32x4 acc[4];
#pragma unroll
    for (int ni = 0; ni < 4; ++ni) acc[ni] = (f32x4){0.f, 0.f, 0.f, 0.f};
#pragma unroll 8
    for (int ks = 0; ks < 32; ++ks) {
        bf16x8 a = *(const bf16x8*)(pa + ks * 64);
#pragma unroll
        for (int ni = 0; ni < 4; ++ni) {
            bf16x8 b8 = *(const bf16x8*)(pb[ni] + ks * 64);
            acc[ni] = __builtin_amdgcn_mfma_f32_16x16x32_bf16(a, b8, acc[ni], 0, 0, 0);
        }
    }
#pragma unroll
    for (int ni = 0; ni < 4; ++ni) {
        int n = ni * 16 + (lane & 15);
        float vb = ldf(bb, (size_t)n, f);
#pragma unroll
        for (int r = 0; r < 4; ++r) {
            int m = m0 + ((lane >> 4) << 2) + r;
            int b = m >> 11, s = m & 2047;
            float v = acc[ni][r] + vb;
            if (!isV) KT[((size_t)b * 64 + n) * 2048 + s] = v;
            else      VTo[((size_t)b * 64 + n) * 2048 + s] = f2bs(v);
        }
    }
}

// ---- heads = P @ V, direct-fragment MFMA. P read dyn-dtype from d_out. ----
__global__ __launch_bounds__(256) void pv_mfma(
    const void* __restrict__ P, const u16* __restrict__ VT,
    u16* __restrict__ Hb, const int* __restrict__ dflag)
{
    const int f = *dflag;
    const int lane = threadIdx.x & 63, wid = threadIdx.x >> 6;
    const int bh = blockIdx.y, b = bh >> 4;
    const int m0 = blockIdx.x * 64 + wid * 16;
    const int rA = m0 + (lane & 15);
    const int kel = (lane >> 4) * 8;
    const size_t pbase = OUT_ELEMS + ((size_t)bh * SEQ + rA) * SEQ + kel;
    const char* pb[4];
#pragma unroll
    for (int ni = 0; ni < 4; ++ni)
        pb[ni] = (const char*)(VT + ((size_t)b * 64 + ni * 16 + (lane & 15)) * 2048 + kel);

    f32x4 acc[4];
#pragma unroll
    for (int ni = 0; ni < 4; ++ni) acc[ni] = (f32x4){0.f, 0.f, 0.f, 0.f};

    if (f) {
        const float* ap = (const float*)P + pbase;
#pragma unroll 8
        for (int ks = 0; ks < 64; ++ks) {
            float4 x = *(const float4*)(ap + ks * 32);
            float4 y = *(const float4*)(ap + ks * 32 + 4);
            union { u16x8 u; bf16x8 b8; } cv;
            cv.u[0] = f2bs(x.x); cv.u[1] = f2bs(x.y); cv.u[2] = f2bs(x.z); cv.u[3] = f2bs(x.w);
            cv.u[4] = f2bs(y.x); cv.u[5] = f2bs(y.y); cv.u[6] = f2bs(y.z); cv.u[7] = f2bs(y.w);
#pragma unroll
            for (int ni = 0; ni < 4; ++ni) {
                bf16x8 b8 = *(const bf16x8*)(pb[ni] + ks * 64);
                acc[ni] = __builtin_amdgcn_mfma_f32_16x16x32_bf16(cv.b8, b8, acc[ni], 0, 0, 0);
            }
        }
    } else {
        const u16* ap = (const u16*)P + pbase;
#pragma unroll 8
        for (int ks = 0; ks < 64; ++ks) {
            bf16x8 a = *(const bf16x8*)(ap + ks * 32);
#pragma unroll
            for (int ni = 0; ni < 4; ++ni) {
                bf16x8 b8 = *(const bf16x8*)(pb[ni] + ks * 64);
                acc[ni] = __builtin_amdgcn_mfma_f32_16x16x32_bf16(a, b8, acc[ni], 0, 0, 0);
            }
        }
    }
    // Hb flat [B,H,S,DK] bf16 (row-major view [4096][1024] for out-proj)
#pragma unroll
    for (int ni = 0; ni < 4; ++ni) {
        int n = ni * 16 + (lane & 15);
#pragma unroll
        for (int r = 0; r < 4; ++r) {
            int m = m0 + ((lane >> 4) << 2) + r;
            Hb[((size_t)bh * SEQ + m) * DK + n] = f2bs(acc[ni][r]);
        }
    }
}

// scores + softmax + attn write, SINGLE pass, scores held in registers. (unchanged)
__global__ __launch_bounds__(256, 2) void attn_scores(
    const float* __restrict__ Qf, const float* __restrict__ Kt,
    void* __restrict__ outp, const int* __restrict__ dflag)
{
    const int f = *dflag;
    __shared__ float Ks[DK][KC];     // 64 KB, [dk][key] transposed chunk
    __shared__ float QsT[DK][QT];    // 4 KB,  [dk][row] transposed Q tile

    const int tid = threadIdx.x;
    const int l = tid & 63, w = tid >> 6;
    const int q0 = blockIdx.x * QT;
    const int h = blockIdx.y, b = blockIdx.z;

    const float* Qbase = Qf + (size_t)b * SEQ * DM + (size_t)h * DK;
    const float* Ktb   = Kt + (size_t)b * DK * SEQ;

    {   // stage Q tile (16 x 64) row-major into Ks-as-temp, transpose into QsT
        float* Qtmp = &Ks[0][0];                 // 16 rows, stride 68
        int qq = tid >> 4, dd = (tid & 15) * 4;
        *(float4*)&Qtmp[qq * 68 + dd] =
            *(const float4*)(Qbase + (size_t)(q0 + qq) * DM + dd);
        __syncthreads();
        int kk = tid >> 2, g = tid & 3;
        float4 v;
        v.x = Qtmp[(g * 4 + 0) * 68 + kk];
        v.y = Qtmp[(g * 4 + 1) * 68 + kk];
        v.z = Qtmp[(g * 4 + 2) * 68 + kk];
        v.w = Qtmp[(g * 4 + 3) * 68 + kk];
        *(float4*)&QsT[kk][g * 4] = v;
    }

    float s[4][32];
#pragma unroll
    for (int i = 0; i < 4; ++i)
#pragma unroll
        for (int j = 0; j < 32; ++j) s[i][j] = 0.f;

#pragma unroll
    for (int c = 0; c < SEQ / KC; ++c) {
        __syncthreads();
#pragma unroll
        for (int r = 0; r < 16; ++r) {
            int idx = tid + 256 * r;
            int kk = idx >> 6, k4 = (idx & 63) * 4;
            *(float4*)&Ks[kk][k4] =
                *(const float4*)(Ktb + (size_t)kk * SEQ + c * KC + k4);
        }
        __syncthreads();

        float acc[4][4];
#pragma unroll
        for (int i = 0; i < 4; ++i)
#pragma unroll
            for (int j = 0; j < 4; ++j) acc[i][j] = 0.f;

#pragma unroll 4
        for (int kk = 0; kk < DK; ++kk) {
            float4 q4 = *(const float4*)&QsT[kk][w * 4];
            float4 k4 = *(const float4*)&Ks[kk][l * 4];
            float qa[4] = {q4.x, q4.y, q4.z, q4.w};
            float kb[4] = {k4.x, k4.y, k4.z, k4.w};
#pragma unroll
            for (int i = 0; i < 4; ++i)
#pragma unroll
                for (int j = 0; j < 4; ++j) acc[i][j] += qa[i] * kb[j];
        }
#pragma unroll
        for (int i = 0; i < 4; ++i)
#pragma unroll
            for (int j = 0; j < 4; ++j) s[i][c * 4 + j] = acc[i][j];
    }

#pragma unroll
    for (int i = 0; i < 4; ++i)
#pragma unroll
        for (int j = 0; j < 32; ++j) s[i][j] *= 0.125f;

    const size_t obase = ((size_t)(b * NH + h) * SEQ + (size_t)(q0 + w * 4)) * SEQ;
#pragma unroll
    for (int i = 0; i < 4; ++i) {
        float m = s[i][0];
#pragma unroll
        for (int j = 1; j < 32; ++j) m = fmaxf(m, s[i][j]);
#pragma unroll
        for (int off = 1; off < 64; off <<= 1)
            m = fmaxf(m, __shfl_xor(m, off));

        float lsum = 0.f;
#pragma unroll
        for (int j = 0; j < 32; ++j) {
            float e = expf(s[i][j] - m);
            s[i][j] = e;
            lsum += e;
        }
#pragma unroll
        for (int off = 1; off < 64; off <<= 1)
            lsum += __shfl_xor(lsum, off);
        const float inv = 1.f / lsum;

        const size_t rb = obase + (size_t)i * SEQ;
        if (f) {
            float* op = (float*)outp + OUT_ELEMS + rb;
#pragma unroll
            for (int c = 0; c < SEQ / KC; ++c) {
                float4 v;
                v.x = s[i][c * 4 + 0] * inv;
                v.y = s[i][c * 4 + 1] * inv;
                v.z = s[i][c * 4 + 2] * inv;
                v.w = s[i][c * 4 + 3] * inv;
                *(float4*)(op + c * KC + l * 4) = v;
            }
        } else {
            __hip_bfloat16* op = (__hip_bfloat16*)outp + OUT_ELEMS + rb;
#pragma unroll
            for (int c = 0; c < SEQ / KC; ++c) {
                __hip_bfloat162 p0, p1;
                p0.x = __float2bfloat16(s[i][c * 4 + 0] * inv);
                p0.y = __float2bfloat16(s[i][c * 4 + 1] * inv);
                p1.x = __float2bfloat16(s[i][c * 4 + 2] * inv);
                p1.y = __float2bfloat16(s[i][c * 4 + 3] * inv);
                *(__hip_bfloat162*)(op + c * KC + l * 4)     = p0;
                *(__hip_bfloat162*)(op + c * KC + l * 4 + 2) = p1;
            }
        }
    }
}

extern "C" void kernel_launch(void* const* d_in, const int* in_sizes, int n_in,
                              void* d_out, int out_size, void* d_ws, size_t ws_size,
                              hipStream_t stream) {
    const void* query = d_in[0];
    const void* key   = d_in[1];
    const void* value = d_in[2];
    const void* w_q = d_in[3];
    const void* b_q = d_in[4];
    const void* w_k = d_in[5];
    const void* b_k = d_in[6];
    const void* w_v = d_in[7];
    const void* b_v = d_in[8];
    const void* w_o = d_in[9];
    const void* b_o = d_in[10];

    // ---- workspace layout (~54 MB) ----
    char* wsb = (char*)d_ws;
    int* flag = (int*)wsb;
    size_t off = 256;
    float* Qf = (float*)(wsb + off); off += (size_t)4096 * 1024 * 4;  // 16 MB fp32 Q
    float* KT = (float*)(wsb + off); off += (size_t)2 * 64 * 2048 * 4; // 1 MB fp32 K^T
    u16* VT   = (u16*)(wsb + off);   off += (size_t)2 * 64 * 2048 * 2; // 0.5 MB bf16 V^T
    u16* Xq   = (u16*)(wsb + off);   off += (size_t)4096 * 1024 * 2;   // 8 MB
    u16* Xk   = (u16*)(wsb + off);   off += (size_t)4096 * 1024 * 2;
    u16* Xv   = (u16*)(wsb + off);   off += (size_t)4096 * 1024 * 2;
    u16* WqT  = (u16*)(wsb + off);   off += (size_t)1024 * 1024 * 2;   // 2 MB
    u16* WoT  = (u16*)(wsb + off);   off += (size_t)1024 * 1024 * 2;
    u16* WkT  = (u16*)(wsb + off);   off += (size_t)64 * 1024 * 2;
    u16* WvT  = (u16*)(wsb + off);   off += (size_t)64 * 1024 * 2;
    u16* Hb   = (u16*)(wsb + off);   off += (size_t)4096 * 1024 * 2;   // 8 MB heads bf16

    // 0) dtype detect
    detect_dtype<<<1, 64, 0, stream>>>((const unsigned int*)query, flag);

    // 1) bf16 copies of activations + K-major weight transposes
    conv_bf16<<<2048, 256, 0, stream>>>(query, Xq, flag);
    conv_bf16<<<2048, 256, 0, stream>>>(key,   Xk, flag);
    conv_bf16<<<2048, 256, 0, stream>>>(value, Xv, flag);
    conv_wT<<<dim3(16, 16), 256, 0, stream>>>(w_q, WqT, 1024, 1024, flag);
    conv_wT<<<dim3(16, 16), 256, 0, stream>>>(w_o, WoT, 1024, 1024, flag);
    conv_wT<<<dim3(1, 16),  256, 0, stream>>>(w_k, WkT, 1024, 64, flag);
    conv_wT<<<dim3(1, 16),  256, 0, stream>>>(w_v, WvT, 1024, 64, flag);

    // 2) Q projection (MFMA, fp32 out for attn_scores)
    gemm_mfma<<<dim3(8, 32), 256, 0, stream>>>(
        Xq, WqT, b_q, Qf, 0, 4096, 1024, 1024, flag);

    // 3) K/V projections -> KT fp32 / VT bf16, directly transposed
    proj_kv<<<dim3(64, 1, 2), 256, 0, stream>>>(
        Xk, Xv, WkT, WvT, b_k, b_v, KT, VT, flag);

    // 4) softmax(QK^T/8) -> attn region of d_out
    attn_scores<<<dim3(SEQ / QT, NH, 2), 256, 0, stream>>>(Qf, KT, d_out, flag);

    // 5) heads = P @ V (MFMA, direct frags) -> Hb bf16
    pv_mfma<<<dim3(32, 32), 256, 0, stream>>>(d_out, VT, Hb, flag);

    // 6) out = heads @ w_o + b_o (MFMA) -> out region of d_out
    gemm_mfma<<<dim3(8, 32), 256, 0, stream>>>(
        Hb, WoT, b_o, d_out, 1, 4096, 1024, 1024, flag);
}

// Round 3
// 848.083 us; speedup vs baseline: 3.5346x; 1.3410x over previous
//
#include <hip/hip_runtime.h>
#include <hip/hip_bf16.h>

#define SEQ 2048
#define DM  1024
#define NH  16
#define DK  64
#define OUT_ELEMS ((size_t)2 * SEQ * DM)   // 4194304, element offset of attn in d_out

typedef unsigned short u16;
typedef _Float16 f16;
typedef __bf16 bf16x8 __attribute__((ext_vector_type(8)));
typedef f16    f16x8  __attribute__((ext_vector_type(8)));
typedef float  f32x4  __attribute__((ext_vector_type(4)));
typedef u16    u16x8  __attribute__((ext_vector_type(8)));
typedef u16    u16x4  __attribute__((ext_vector_type(4)));

__device__ __forceinline__ u16 f2bs(float x) {
    union { __hip_bfloat16 h; u16 s; } u; u.h = __float2bfloat16(x); return u.s;
}
__device__ __forceinline__ float bs2f(u16 s) {
    union { __hip_bfloat16 h; u16 s; } u; u.s = s; return __bfloat162float(u.h);
}
__device__ __forceinline__ float ldf(const void* p, size_t i, int f) {
    return f ? ((const float*)p)[i] : bs2f(((const u16*)p)[i]);
}

// ---- dtype detection: sample 64 words of query, vote on bf16 exponent stats ----
__global__ void detect_dtype(const unsigned int* q, int* flag) {
    unsigned w = q[(size_t)threadIdx.x * 30011 + 7];
    int e = (w >> 7) & 0xFF;
    int inr = (e >= 115 && e <= 131) ? 1 : 0;
    unsigned long long bal = __ballot(inr);
    if (threadIdx.x == 0) *flag = (__popcll(bal) >= 32) ? 0 : 1;  // 0=bf16, 1=fp32
}

// ---- elementwise convert (or copy) to bf16, 8 elems/thread ----
__global__ __launch_bounds__(256) void conv_bf16(const void* __restrict__ src,
                                                 u16* __restrict__ dst,
                                                 const int* __restrict__ dflag) {
    const int f = *dflag;
    size_t i = ((size_t)blockIdx.x * 256 + threadIdx.x) * 8;
    if (f) {
        const float* s = (const float*)src + i;
        float4 a = *(const float4*)s, b = *(const float4*)(s + 4);
        u16x8 u;
        u[0] = f2bs(a.x); u[1] = f2bs(a.y); u[2] = f2bs(a.z); u[3] = f2bs(a.w);
        u[4] = f2bs(b.x); u[5] = f2bs(b.y); u[6] = f2bs(b.z); u[7] = f2bs(b.w);
        *(u16x8*)(dst + i) = u;
    } else {
        *(u16x8*)(dst + i) = *(const u16x8*)((const u16*)src + i);
    }
}

// ---- W[K][N] (dyn dtype) -> WT[N][K] bf16, 64x64 LDS tile ----
__global__ __launch_bounds__(256) void conv_wT(const void* __restrict__ W, u16* __restrict__ WT,
                                               int Kd, int Nd, const int* __restrict__ dflag) {
    const int f = *dflag;
    __shared__ float t[64][65];
    const int tid = threadIdx.x;
    const int k0 = blockIdx.y * 64, n0 = blockIdx.x * 64;
#pragma unroll
    for (int it = 0; it < 4; ++it) {
        int idx = tid + 256 * it;
        int rr = idx >> 4, c4 = (idx & 15) * 4;
        size_t gi = (size_t)(k0 + rr) * Nd + n0 + c4;
        if (f) {
            float4 v = *(const float4*)((const float*)W + gi);
            t[rr][c4] = v.x; t[rr][c4 + 1] = v.y; t[rr][c4 + 2] = v.z; t[rr][c4 + 3] = v.w;
        } else {
            u16x4 u = *(const u16x4*)((const u16*)W + gi);
            t[rr][c4] = bs2f(u[0]); t[rr][c4 + 1] = bs2f(u[1]);
            t[rr][c4 + 2] = bs2f(u[2]); t[rr][c4 + 3] = bs2f(u[3]);
        }
    }
    __syncthreads();
#pragma unroll
    for (int it = 0; it < 4; ++it) {
        int idx = tid + 256 * it;
        int rr = idx >> 4, c4 = (idx & 15) * 4;
        u16x4 u;
        u[0] = f2bs(t[c4][rr]);     u[1] = f2bs(t[c4 + 1][rr]);
        u[2] = f2bs(t[c4 + 2][rr]); u[3] = f2bs(t[c4 + 3][rr]);
        *(u16x4*)(WT + (size_t)(n0 + rr) * Kd + k0 + c4) = u;
    }
}

// ---- MFMA GEMM: C[M,N] = A[M,K](bf16) @ BT[N,K](bf16)^T + bias ----
// outMode: 0 = fp32, 1 = dyn dtype (d_out), 2 = f16
__global__ __launch_bounds__(256) void gemm_mfma(
    const u16* __restrict__ A, const u16* __restrict__ BT,
    const void* __restrict__ bias, void* __restrict__ C, int outMode,
    int Md, int Nd, int Kd, const int* __restrict__ dflag)
{
    const int f = *dflag;
    __shared__ u16 Als[128 * 64];
    __shared__ u16 Bls[128 * 64];
    const int tid = threadIdx.x;
    const int lane = tid & 63, wid = tid >> 6;
    const int wr = wid >> 1, wc = wid & 1;
    const int m0 = blockIdx.y * 128, n0 = blockIdx.x * 128;

    const char* pa[4]; const char* pb[4]; int lof[4];
#pragma unroll
    for (int it = 0; it < 4; ++it) {
        int tb = wid * 4096 + it * 1024 + lane * 16;
        int r = tb >> 7, o = tb & 127;
        lof[it] = (r << 7) | (o ^ ((r & 7) << 4));
        pa[it] = (const char*)(A  + (size_t)(m0 + r) * Kd) + o;
        pb[it] = (const char*)(BT + (size_t)(n0 + r) * Kd) + o;
    }

    f32x4 acc[4][4];
#pragma unroll
    for (int i = 0; i < 4; ++i)
#pragma unroll
        for (int j = 0; j < 4; ++j) acc[i][j] = (f32x4){0.f, 0.f, 0.f, 0.f};

    u16x8 ra[4], rb[4];
#pragma unroll
    for (int it = 0; it < 4; ++it) {
        ra[it] = *(const u16x8*)(pa[it]);
        rb[it] = *(const u16x8*)(pb[it]);
    }
    const int NT = Kd >> 6;
    for (int kt = 0; kt < NT; ++kt) {
        __syncthreads();
#pragma unroll
        for (int it = 0; it < 4; ++it) {
            *(u16x8*)((char*)Als + lof[it]) = ra[it];
            *(u16x8*)((char*)Bls + lof[it]) = rb[it];
        }
        if (kt + 1 < NT) {
#pragma unroll
            for (int it = 0; it < 4; ++it) {
                ra[it] = *(const u16x8*)(pa[it] + (kt + 1) * 128);
                rb[it] = *(const u16x8*)(pb[it] + (kt + 1) * 128);
            }
        }
        __syncthreads();
#pragma unroll
        for (int ks = 0; ks < 2; ++ks) {
            const int kb = ks * 64 + ((lane >> 4) << 4);
            bf16x8 afr[4], bfr[4];
#pragma unroll
            for (int mi = 0; mi < 4; ++mi) {
                int rr = wr * 64 + mi * 16 + (lane & 15);
                afr[mi] = *(const bf16x8*)((const char*)Als + ((rr << 7) | (kb ^ ((rr & 7) << 4))));
            }
#pragma unroll
            for (int ni = 0; ni < 4; ++ni) {
                int rr = wc * 64 + ni * 16 + (lane & 15);
                bfr[ni] = *(const bf16x8*)((const char*)Bls + ((rr << 7) | (kb ^ ((rr & 7) << 4))));
            }
#pragma unroll
            for (int mi = 0; mi < 4; ++mi)
#pragma unroll
                for (int ni = 0; ni < 4; ++ni)
                    acc[mi][ni] = __builtin_amdgcn_mfma_f32_16x16x32_bf16(
                        afr[mi], bfr[ni], acc[mi][ni], 0, 0, 0);
        }
    }

#pragma unroll
    for (int mi = 0; mi < 4; ++mi)
#pragma unroll
        for (int ni = 0; ni < 4; ++ni) {
            int n = n0 + wc * 64 + ni * 16 + (lane & 15);
            float vb = ldf(bias, (size_t)n, f);
#pragma unroll
            for (int r = 0; r < 4; ++r) {
                int m = m0 + wr * 64 + mi * 16 + ((lane >> 4) << 2) + r;
                float v = acc[mi][ni][r] + vb;
                size_t ci = (size_t)m * Nd + n;
                if (outMode == 2)           ((f16*)C)[ci] = (f16)v;
                else if (outMode == 0 || f) ((float*)C)[ci] = v;
                else ((__hip_bfloat16*)C)[ci] = __float2bfloat16(v);
            }
        }
}

// ---- K/V projection, direct-fragment MFMA ----
// z=0: Kh[b][s][dk] f16 row-major; z=1: VT[b][dk][s] f16 transposed.
__global__ __launch_bounds__(256) void proj_kv(
    const u16* __restrict__ Xk, const u16* __restrict__ Xv,
    const u16* __restrict__ WkT, const u16* __restrict__ WvT,
    const void* __restrict__ bk, const void* __restrict__ bvv,
    f16* __restrict__ Kh, f16* __restrict__ VTo,
    const int* __restrict__ dflag)
{
    const int f = *dflag;
    const int isV = blockIdx.z;
    const u16* X  = isV ? Xv : Xk;
    const u16* WT = isV ? WvT : WkT;
    const void* bb = isV ? bvv : bk;
    const int lane = threadIdx.x & 63, wid = threadIdx.x >> 6;
    const int m0 = blockIdx.x * 64 + wid * 16;
    const int rA = m0 + (lane & 15);
    const int kel = (lane >> 4) * 8;
    const char* pa = (const char*)(X + (size_t)rA * 1024 + kel);
    const char* pb[4];
#pragma unroll
    for (int ni = 0; ni < 4; ++ni)
        pb[ni] = (const char*)(WT + (size_t)(ni * 16 + (lane & 15)) * 1024 + kel);

    f32x4 acc[4];
#pragma unroll
    for (int ni = 0; ni < 4; ++ni) acc[ni] = (f32x4){0.f, 0.f, 0.f, 0.f};
#pragma unroll 8
    for (int ks = 0; ks < 32; ++ks) {
        bf16x8 a = *(const bf16x8*)(pa + ks * 64);
#pragma unroll
        for (int ni = 0; ni < 4; ++ni) {
            bf16x8 b8 = *(const bf16x8*)(pb[ni] + ks * 64);
            acc[ni] = __builtin_amdgcn_mfma_f32_16x16x32_bf16(a, b8, acc[ni], 0, 0, 0);
        }
    }
#pragma unroll
    for (int ni = 0; ni < 4; ++ni) {
        int n = ni * 16 + (lane & 15);
        float vb = ldf(bb, (size_t)n, f);
#pragma unroll
        for (int r = 0; r < 4; ++r) {
            int m = m0 + ((lane >> 4) << 2) + r;
            int b = m >> 11, s = m & 2047;
            float v = acc[ni][r] + vb;
            if (!isV) Kh[((size_t)b * SEQ + s) * DK + n] = (f16)v;
            else      VTo[((size_t)b * DK + n) * SEQ + s] = (f16)v;
        }
    }
}

// ---- fused scores + softmax + P-write + PV, all-MFMA ----
// Block = 16 q rows x one (b,h); wave w owns keys [w*512, w*512+512).
// Scores in 128 VGPRs/lane; P bounced through XOR-swizzled LDS for
// coalesced stores AND re-read as fp16 A-frags for the PV MFMA.
__global__ __launch_bounds__(256, 2) void attn_fused(
    const f16* __restrict__ Qh, const f16* __restrict__ Kh,
    const f16* __restrict__ VT, u16* __restrict__ Hb,
    void* __restrict__ outp, const int* __restrict__ dflag)
{
    const int f = *dflag;
    __shared__ float ldsP[8192];     // 32 KB: 8 KB/wave bounce; aliased as [4][16][64] reduce buf
    __shared__ float redM[4][16];
    __shared__ float redL[4][16];

    const int tid = threadIdx.x;
    const int lane = tid & 63, w = tid >> 6;
    const int g = lane >> 4, c = lane & 15;
    const int q0 = blockIdx.x * 16;
    const int bh = blockIdx.y, b = bh >> 4, h = bh & 15;

    // Q A-frags (k-steps 0,1) direct from global
    const f16* qp = Qh + ((size_t)(b * SEQ + q0 + c) * DM + h * DK + g * 8);
    const f16x8 qf0 = *(const f16x8*)qp;
    const f16x8 qf1 = *(const f16x8*)(qp + 32);

    // QK^T: 32 key-tiles, B-frags direct from global (L2-resident K)
    const f16* kp0 = Kh + ((size_t)(b * SEQ + w * 512 + c) * DK + g * 8);
    f32x4 sc[32];
#pragma unroll
    for (int t = 0; t < 32; ++t) {
        const f16* kp = kp0 + (size_t)t * 16 * DK;
        f32x4 a = (f32x4){0.f, 0.f, 0.f, 0.f};
        a = __builtin_amdgcn_mfma_f32_16x16x32_f16(qf0, *(const f16x8*)kp, a, 0, 0, 0);
        a = __builtin_amdgcn_mfma_f32_16x16x32_f16(qf1, *(const f16x8*)(kp + 32), a, 0, 0, 0);
        sc[t] = a;
    }

    // softmax: scale, global row max, exp, global row sum (rows = g*4+r)
    float mr[4] = {-3.0e38f, -3.0e38f, -3.0e38f, -3.0e38f};
#pragma unroll
    for (int t = 0; t < 32; ++t)
#pragma unroll
        for (int r = 0; r < 4; ++r) {
            float s = sc[t][r] * 0.125f;
            sc[t][r] = s;
            mr[r] = fmaxf(mr[r], s);
        }
#pragma unroll
    for (int off = 1; off < 16; off <<= 1)
#pragma unroll
        for (int r = 0; r < 4; ++r) mr[r] = fmaxf(mr[r], __shfl_xor(mr[r], off));
    if (c == 0) {
#pragma unroll
        for (int r = 0; r < 4; ++r) redM[w][g * 4 + r] = mr[r];
    }
    __syncthreads();
    float M[4], li[4];
#pragma unroll
    for (int r = 0; r < 4; ++r) {
        int row = g * 4 + r;
        M[r] = fmaxf(fmaxf(redM[0][row], redM[1][row]), fmaxf(redM[2][row], redM[3][row]));
        li[r] = 0.f;
    }
#pragma unroll
    for (int t = 0; t < 32; ++t)
#pragma unroll
        for (int r = 0; r < 4; ++r) {
            float e = __expf(sc[t][r] - M[r]);
            sc[t][r] = e;
            li[r] += e;
        }
#pragma unroll
    for (int off = 1; off < 16; off <<= 1)
#pragma unroll
        for (int r = 0; r < 4; ++r) li[r] += __shfl_xor(li[r], off);
    if (c == 0) {
#pragma unroll
        for (int r = 0; r < 4; ++r) redL[w][g * 4 + r] = li[r];
    }
    __syncthreads();
    float inv[4];
#pragma unroll
    for (int r = 0; r < 4; ++r) {
        int row = g * 4 + r;
        inv[r] = 1.f / (redL[0][row] + redL[1][row] + redL[2][row] + redL[3][row]);
    }

    // epilogue: 4 passes of 128 keys — LDS bounce -> coalesced P store + PV MFMA
    char* Pl = (char*)ldsP + w * 8192;
    f32x4 acc2[4];
#pragma unroll
    for (int nt = 0; nt < 4; ++nt) acc2[nt] = (f32x4){0.f, 0.f, 0.f, 0.f};
    const size_t pgbase = ((size_t)bh * SEQ + q0) * SEQ;

#pragma unroll
    for (int pass = 0; pass < 4; ++pass) {
        // (a) normalized P -> swizzled LDS (fp32)
#pragma unroll
        for (int t2 = 0; t2 < 8; ++t2) {
            int t = pass * 8 + t2;
            int col = t2 * 16 + c;
#pragma unroll
            for (int r = 0; r < 4; ++r) {
                int row = g * 4 + r;
                *(float*)(Pl + (row << 9) + ((col << 2) ^ ((row & 7) << 4))) = sc[t][r] * inv[r];
            }
        }
        __syncthreads();
        // (b) coalesced P store (512B row segments fp32 / 256B bf16)
#pragma unroll
        for (int it = 0; it < 8; ++it) {
            int u = it * 64 + lane;
            int row = u >> 5, c4 = u & 31;
            float4 v = *(const float4*)(Pl + (row << 9) + ((c4 << 4) ^ ((row & 7) << 4)));
            size_t gi = pgbase + (size_t)row * SEQ + w * 512 + pass * 128 + c4 * 4;
            if (f) {
                *(float4*)((float*)outp + OUT_ELEMS + gi) = v;
            } else {
                u16x4 o;
                o[0] = f2bs(v.x); o[1] = f2bs(v.y); o[2] = f2bs(v.z); o[3] = f2bs(v.w);
                *(u16x4*)((u16*)outp + OUT_ELEMS + gi) = o;
            }
        }
        // (c) PV over this pass's 128 keys (A from LDS, B direct from VT)
#pragma unroll
        for (int ks = 0; ks < 4; ++ks) {
            int row = c;
            int kb = g * 32 + ks * 128;
            float4 x = *(const float4*)(Pl + (row << 9) + (kb ^ ((row & 7) << 4)));
            float4 y = *(const float4*)(Pl + (row << 9) + ((kb + 16) ^ ((row & 7) << 4)));
            f16x8 pa;
            pa[0] = (f16)x.x; pa[1] = (f16)x.y; pa[2] = (f16)x.z; pa[3] = (f16)x.w;
            pa[4] = (f16)y.x; pa[5] = (f16)y.y; pa[6] = (f16)y.z; pa[7] = (f16)y.w;
            const f16* vp = VT + (size_t)(b * DK + c) * SEQ + w * 512 + pass * 128 + ks * 32 + g * 8;
#pragma unroll
            for (int nt = 0; nt < 4; ++nt) {
                f16x8 vb = *(const f16x8*)(vp + (size_t)nt * 16 * SEQ);
                acc2[nt] = __builtin_amdgcn_mfma_f32_16x16x32_f16(pa, vb, acc2[nt], 0, 0, 0);
            }
        }
        __syncthreads();
    }

    // cross-wave PV reduce -> Hb (flat [B,H,S,DK] bf16)
    float* accb = ldsP;   // [4][16][64]
#pragma unroll
    for (int nt = 0; nt < 4; ++nt)
#pragma unroll
        for (int r = 0; r < 4; ++r)
            accb[((w * 16 + g * 4 + r) << 6) + nt * 16 + c] = acc2[nt][r];
    __syncthreads();
    {
        int q = tid >> 4, d4 = (tid & 15) * 4;
        float4 v0 = *(const float4*)&accb[((0 * 16 + q) << 6) + d4];
        float4 v1 = *(const float4*)&accb[((1 * 16 + q) << 6) + d4];
        float4 v2 = *(const float4*)&accb[((2 * 16 + q) << 6) + d4];
        float4 v3 = *(const float4*)&accb[((3 * 16 + q) << 6) + d4];
        u16x4 o;
        o[0] = f2bs(v0.x + v1.x + v2.x + v3.x);
        o[1] = f2bs(v0.y + v1.y + v2.y + v3.y);
        o[2] = f2bs(v0.z + v1.z + v2.z + v3.z);
        o[3] = f2bs(v0.w + v1.w + v2.w + v3.w);
        *(u16x4*)(Hb + ((size_t)bh * SEQ + q0 + q) * DK + d4) = o;
    }
}

extern "C" void kernel_launch(void* const* d_in, const int* in_sizes, int n_in,
                              void* d_out, int out_size, void* d_ws, size_t ws_size,
                              hipStream_t stream) {
    const void* query = d_in[0];
    const void* key   = d_in[1];
    const void* value = d_in[2];
    const void* w_q = d_in[3];
    const void* b_q = d_in[4];
    const void* w_k = d_in[5];
    const void* b_k = d_in[6];
    const void* w_v = d_in[7];
    const void* b_v = d_in[8];
    const void* w_o = d_in[9];
    const void* b_o = d_in[10];

    // ---- workspace layout (~46 MB) ----
    char* wsb = (char*)d_ws;
    int* flag = (int*)wsb;
    size_t off = 256;
    f16* Qh  = (f16*)(wsb + off); off += (size_t)4096 * 1024 * 2;   // 8 MB f16 Q
    f16* Kh  = (f16*)(wsb + off); off += (size_t)2 * 2048 * 64 * 2; // 0.5 MB f16 K
    f16* VT  = (f16*)(wsb + off); off += (size_t)2 * 64 * 2048 * 2; // 0.5 MB f16 V^T
    u16* Xq  = (u16*)(wsb + off); off += (size_t)4096 * 1024 * 2;   // 8 MB
    u16* Xk  = (u16*)(wsb + off); off += (size_t)4096 * 1024 * 2;
    u16* Xv  = (u16*)(wsb + off); off += (size_t)4096 * 1024 * 2;
    u16* WqT = (u16*)(wsb + off); off += (size_t)1024 * 1024 * 2;   // 2 MB
    u16* WoT = (u16*)(wsb + off); off += (size_t)1024 * 1024 * 2;
    u16* WkT = (u16*)(wsb + off); off += (size_t)64 * 1024 * 2;
    u16* WvT = (u16*)(wsb + off); off += (size_t)64 * 1024 * 2;
    u16* Hb  = (u16*)(wsb + off); off += (size_t)4096 * 1024 * 2;   // 8 MB heads bf16

    // 0) dtype detect
    detect_dtype<<<1, 64, 0, stream>>>((const unsigned int*)query, flag);

    // 1) bf16 copies of activations + K-major weight transposes
    conv_bf16<<<2048, 256, 0, stream>>>(query, Xq, flag);
    conv_bf16<<<2048, 256, 0, stream>>>(key,   Xk, flag);
    conv_bf16<<<2048, 256, 0, stream>>>(value, Xv, flag);
    conv_wT<<<dim3(16, 16), 256, 0, stream>>>(w_q, WqT, 1024, 1024, flag);
    conv_wT<<<dim3(16, 16), 256, 0, stream>>>(w_o, WoT, 1024, 1024, flag);
    conv_wT<<<dim3(1, 16),  256, 0, stream>>>(w_k, WkT, 1024, 64, flag);
    conv_wT<<<dim3(1, 16),  256, 0, stream>>>(w_v, WvT, 1024, 64, flag);

    // 2) Q projection (MFMA, f16 out for attn)
    gemm_mfma<<<dim3(8, 32), 256, 0, stream>>>(
        Xq, WqT, b_q, Qh, 2, 4096, 1024, 1024, flag);

    // 3) K/V projections -> Kh row-major f16, VT transposed f16
    proj_kv<<<dim3(64, 1, 2), 256, 0, stream>>>(
        Xk, Xv, WkT, WvT, b_k, b_v, Kh, VT, flag);

    // 4) fused QK^T -> softmax -> P store + PV -> Hb
    attn_fused<<<dim3(SEQ / 16, 2 * NH), 256, 0, stream>>>(
        Qh, Kh, VT, Hb, d_out, flag);

    // 5) out = heads @ w_o + b_o (MFMA) -> out region of d_out
    gemm_mfma<<<dim3(8, 32), 256, 0, stream>>>(
        Hb, WoT, b_o, d_out, 1, 4096, 1024, 1024, flag);
}